// Round 10
// baseline (337.340 us; speedup 1.0000x reference)
//
#include <hip/hip_runtime.h>
#include <hip/hip_bf16.h>
#include <math.h>

#define BB 2
#define SS 2048
#define DD 1024
#define HH 16
#define DKK 64

typedef __bf16 bf16_t;
typedef _Float16 f16_t;
typedef __attribute__((ext_vector_type(8))) __bf16 bf16x8;
typedef __attribute__((ext_vector_type(4))) __bf16 bf16x4;
typedef __attribute__((ext_vector_type(8))) _Float16 f16x8;
typedef __attribute__((ext_vector_type(4))) _Float16 f16x4;
typedef __attribute__((ext_vector_type(4))) float f32x4;

// async global->LDS, 16B per lane; lds base must be wave-uniform (lane*16 implicit)
#define GLD_LDS(gp, lp) __builtin_amdgcn_global_load_lds( \
    (const __attribute__((address_space(1))) void*)(gp),  \
    (__attribute__((address_space(3))) void*)(lp), 16, 0, 0)

// ---------------------------------------------------------------- cast kernels
__global__ void cast_f32_bf16(const float* __restrict__ in, bf16_t* __restrict__ out, int n) {
    int i = blockIdx.x * blockDim.x + threadIdx.x;
    int stride = gridDim.x * blockDim.x;
    for (; i < n; i += stride) out[i] = (bf16_t)in[i];
}

__global__ void cast_split(const float* __restrict__ in, bf16_t* __restrict__ hi,
                           bf16_t* __restrict__ lo, int n) {
    int i = blockIdx.x * blockDim.x + threadIdx.x;
    int stride = gridDim.x * blockDim.x;
    for (; i < n; i += stride) {
        float v = in[i];
        bf16_t h = (bf16_t)v;
        hi[i] = h;
        lo[i] = (bf16_t)(v - (float)h);
    }
}

// ---------------------------------------------------------------- fused Q+K x3 GEMM -> fp16 split-head outputs
__global__ __launch_bounds__(256) void gemm_qk(const bf16_t* __restrict__ Ah,
                                               const bf16_t* __restrict__ Al,
                                               const bf16_t* __restrict__ Bh,
                                               const bf16_t* __restrict__ Bl,
                                               const float* __restrict__ bq,
                                               const float* __restrict__ bk,
                                               f16_t* __restrict__ q_o,
                                               f16_t* __restrict__ k_o,
                                               int K) {
    __shared__ __align__(16) bf16_t lds[16384];  // 4 chunks of 128x32
    bf16_t* sAh = lds;
    bf16_t* sAl = lds + 4096;
    bf16_t* sBh = lds + 8192;
    bf16_t* sBl = lds + 12288;

    const int tid  = threadIdx.x;
    const int wv   = tid >> 6;
    const int lane = tid & 63;
    const int quad = lane >> 4;
    const int l15  = lane & 15;
    const int wr   = wv >> 1;
    const int wc   = wv & 1;
    const int row0 = blockIdx.y * 128;
    const int col0 = blockIdx.x * 128;

    f32x4 acc[4][4] = {};

    const int srow = tid >> 2;
    const int scol = (tid & 3) * 8;
    const long aoff = (long)(row0 + srow) * K + scol;
    const long boff = (long)(col0 + srow) * K + scol;

#pragma unroll 1
    for (int kb = 0; kb < K; kb += 32) {
#pragma unroll
        for (int p = 0; p < 2; ++p) {
            const long go = (long)p * 64 * K + kb;
            const int lo = p * 2048 + wv * 512;
            GLD_LDS(Ah + aoff + go, sAh + lo);
            GLD_LDS(Al + aoff + go, sAl + lo);
            GLD_LDS(Bh + boff + go, sBh + lo);
            GLD_LDS(Bl + boff + go, sBl + lo);
        }
        __syncthreads();

        bf16x8 afh[4], afl[4];
#pragma unroll
        for (int mt = 0; mt < 4; ++mt) {
            const int ar = wr * 64 + mt * 16 + l15;
            afh[mt] = *(const bf16x8*)&sAh[ar * 32 + quad * 8];
            afl[mt] = *(const bf16x8*)&sAl[ar * 32 + quad * 8];
        }
#pragma unroll
        for (int nt = 0; nt < 4; ++nt) {
            const int br = wc * 64 + nt * 16 + l15;
            bf16x8 bh = *(const bf16x8*)&sBh[br * 32 + quad * 8];
            bf16x8 bl = *(const bf16x8*)&sBl[br * 32 + quad * 8];
#pragma unroll
            for (int mt = 0; mt < 4; ++mt) {
                acc[mt][nt] = __builtin_amdgcn_mfma_f32_16x16x32_bf16(afh[mt], bh, acc[mt][nt], 0, 0, 0);
                acc[mt][nt] = __builtin_amdgcn_mfma_f32_16x16x32_bf16(afh[mt], bl, acc[mt][nt], 0, 0, 0);
                acc[mt][nt] = __builtin_amdgcn_mfma_f32_16x16x32_bf16(afl[mt], bh, acc[mt][nt], 0, 0, 0);
            }
        }
        __syncthreads();
    }

    const bool isK = (col0 >= 1024);
    const float* bias = isK ? bk : bq;
    f16_t* op = isK ? k_o : q_o;
#pragma unroll
    for (int nt = 0; nt < 4; ++nt) {
        const int gcol = (col0 & 1023) + wc * 64 + nt * 16 + l15;
        const float bv = bias[gcol];
        const int hq = gcol >> 6, dk = gcol & 63;
#pragma unroll
        for (int mt = 0; mt < 4; ++mt) {
            const int grow0 = row0 + wr * 64 + mt * 16 + quad * 4;
#pragma unroll
            for (int r = 0; r < 4; ++r) {
                int grow = grow0 + r;
                float vv = acc[mt][nt][r] + bv;
                long off = (((long)(grow >> 11) * HH + hq) * SS + (grow & (SS - 1))) * DKK + dk;
                op[off] = (f16_t)vv;
            }
        }
    }
}

// ---------------------------------------------------------------- 64x128 GEMM (V and O projections)
// MODE 0: fp32 out[M,N]; MODE 2: fp16 V^T [B,H,DK,S]
template<int MODE>
__global__ __launch_bounds__(256) void gemm2(const bf16_t* __restrict__ Ah,
                                             const bf16_t* __restrict__ Bh,
                                             const float* __restrict__ bias,
                                             float* __restrict__ outf,
                                             f16_t* __restrict__ oh,
                                             int N, int K) {
    constexpr int ANE = 64 * 32;
    constexpr int BNE = 128 * 32;
    __shared__ __align__(16) bf16_t lds[ANE + BNE];
    bf16_t* Ash = lds;
    bf16_t* Bsh = lds + ANE;

    const int tid  = threadIdx.x;
    const int wv   = tid >> 6;
    const int lane = tid & 63;
    const int quad = lane >> 4;
    const int l15  = lane & 15;
    const int wr   = wv >> 1;
    const int wc   = wv & 1;
    const int row0 = blockIdx.y * 64;
    const int col0 = blockIdx.x * 128;

    f32x4 acc[2][4] = {};

    const int srow = lane >> 2;
    const int scol = (lane & 3) * 8;
    const bf16_t* gA  = Ah + (long)(row0 + wv * 16 + srow) * K + scol;
    const bf16_t* gB0 = Bh + (long)(col0 + wv * 16 + srow) * K + scol;
    const bf16_t* gB1 = Bh + (long)(col0 + (wv + 4) * 16 + srow) * K + scol;
    bf16_t* lA  = Ash + wv * 512;
    bf16_t* lB0 = Bsh + wv * 512;
    bf16_t* lB1 = Bsh + (wv + 4) * 512;

#pragma unroll 1
    for (int kb = 0; kb < K; kb += 32) {
        GLD_LDS(gA + kb, lA);
        GLD_LDS(gB0 + kb, lB0);
        GLD_LDS(gB1 + kb, lB1);
        __syncthreads();

        bf16x8 af[2];
#pragma unroll
        for (int mt = 0; mt < 2; ++mt)
            af[mt] = *(const bf16x8*)&Ash[(wr * 32 + mt * 16 + l15) * 32 + quad * 8];
#pragma unroll
        for (int nt = 0; nt < 4; ++nt) {
            bf16x8 bh = *(const bf16x8*)&Bsh[(wc * 64 + nt * 16 + l15) * 32 + quad * 8];
#pragma unroll
            for (int mt = 0; mt < 2; ++mt)
                acc[mt][nt] = __builtin_amdgcn_mfma_f32_16x16x32_bf16(af[mt], bh, acc[mt][nt], 0, 0, 0);
        }
        __syncthreads();
    }

#pragma unroll
    for (int mt = 0; mt < 2; ++mt) {
#pragma unroll
        for (int nt = 0; nt < 4; ++nt) {
            const int gcol  = col0 + wc * 64 + nt * 16 + l15;
            const float bv  = bias[gcol];
            const int grow0 = row0 + wr * 32 + mt * 16 + quad * 4;
            if constexpr (MODE == 0) {
#pragma unroll
                for (int r = 0; r < 4; ++r)
                    outf[(long)(grow0 + r) * N + gcol] = acc[mt][nt][r] + bv;
            } else {
                const int hq = gcol >> 6, dk = gcol & 63;
                const int bq2 = grow0 >> 11;
                const int s0  = grow0 & (SS - 1);
                f16x4 pk;
#pragma unroll
                for (int r = 0; r < 4; ++r) pk[r] = (f16_t)(acc[mt][nt][r] + bv);
                *(f16x4*)(oh + ((long)(bq2 * HH + hq) * DKK + dk) * SS + s0) = pk;
            }
        }
    }
}

// ---------------------------------------------------------------- MFMA flash attention v3
// fp16 operands, swizzled DMA staging, DOUBLE-BUFFERED K/V (one barrier/iter),
// score scale x8 pre-folded into Q fragment.
__global__ __launch_bounds__(256) void attn_mfma3(const f16_t* __restrict__ Qp,
                                                  const f16_t* __restrict__ Kp,
                                                  const f16_t* __restrict__ Vtp,
                                                  const int* __restrict__ mask,
                                                  bf16_t* __restrict__ ctx,
                                                  int seq_len) {
    __shared__ __align__(16) f16_t Ksh[2][4096];     // swizzled: col-group ^ (row&7)
    __shared__ __align__(16) f16_t Vsh[2][4096];     // swizzled V^T tile [d][key]
    __shared__ __align__(16) f16_t Psh[4][16 * 68];  // stride 68: quad banks 0/8/16/24

    const int tid  = threadIdx.x;
    const int wv   = tid >> 6;
    const int lane = tid & 63;
    const int quad = lane >> 4;
    const int l15  = lane & 15;
    const int bh   = blockIdx.y;
    const int b    = bh >> 4;
    const int h    = bh & 15;
    const int q0   = blockIdx.x * 64 + wv * 16;

    const long kb = (long)bh * SS * DKK;  // same for Vt ([B,H,DK,S])

    // Q fragments (A-layout), pre-scaled by 8 (= 1/dk^-0.5; exact in fp16)
    f16x8 qf[2];
    {
        const f16_t* pq = Qp + kb + (long)(q0 + l15) * DKK + quad * 8;
        qf[0] = *(const f16x8*)pq;
        qf[1] = *(const f16x8*)(pq + 32);
#pragma unroll
        for (int j = 0; j < 8; ++j) { qf[0][j] *= (f16_t)8.0f; qf[1][j] *= (f16_t)8.0f; }
    }

    f32x4 o[4];
    float m[4], l[4];
#pragma unroll
    for (int r = 0; r < 4; ++r) {
        o[r] = (f32x4){0.f, 0.f, 0.f, 0.f};
        m[r] = -1e30f;
        l[r] = 0.f;
    }

    const int* mrow = mask + b * SS;

    // DMA staging: inst i covers rows i*8..i*8+7; lane -> row i*8+(lane>>3),
    // stored col-group sg=lane&7 holds logical group g = sg ^ (row&7)
    const int srow8 = lane >> 3;
    const int gcolB = ((lane & 7) ^ srow8) * 8;

    // prologue: stage tile 0 into buffer 0
#pragma unroll
    for (int p = 0; p < 2; ++p) {
        const int i = wv * 2 + p;
        const int row = i * 8 + srow8;
        GLD_LDS(Kp + kb + (long)row * DKK + gcolB, &Ksh[0][i * 512]);
        GLD_LDS(Vtp + kb + (long)row * SS + gcolB, &Vsh[0][i * 512]);
    }
    __syncthreads();

#pragma unroll 1
    for (int kt = 0; kt < seq_len; kt += 64) {
        const int cur = (kt >> 6) & 1;
        // prefetch next tile into the other buffer (no wait here)
        if (kt + 64 < seq_len) {
            const int nxt = cur ^ 1;
#pragma unroll
            for (int p = 0; p < 2; ++p) {
                const int i = wv * 2 + p;
                const int row = i * 8 + srow8;
                GLD_LDS(Kp + kb + (long)(kt + 64 + row) * DKK + gcolB, &Ksh[nxt][i * 512]);
                GLD_LDS(Vtp + kb + (long)row * SS + (kt + 64) + gcolB, &Vsh[nxt][i * 512]);
            }
        }

        // ---- S = Q K^T (fp16), D[m=q=quad*4+r][n=key=nt*16+l15]
        f32x4 s[4];
#pragma unroll
        for (int nt = 0; nt < 4; ++nt) s[nt] = (f32x4){0.f, 0.f, 0.f, 0.f};
#pragma unroll
        for (int nt = 0; nt < 4; ++nt) {
            const int kr = nt * 16 + l15;
#pragma unroll
            for (int dt = 0; dt < 2; ++dt) {
                f16x8 kf = *(const f16x8*)&Ksh[cur][kr * 64 + (((dt * 4 + quad) ^ (l15 & 7)) << 3)];
                s[nt] = __builtin_amdgcn_mfma_f32_16x16x32_f16(qf[dt], kf, s[nt], 0, 0, 0);
            }
        }

        // ---- key-padding mask (scale already folded into Q)
#pragma unroll
        for (int nt = 0; nt < 4; ++nt) {
            int keep = mrow[kt + nt * 16 + l15];
#pragma unroll
            for (int r = 0; r < 4; ++r)
                s[nt][r] = keep ? s[nt][r] : -1e30f;
        }

        // ---- row max over keys
        float tm[4];
#pragma unroll
        for (int r = 0; r < 4; ++r)
            tm[r] = fmaxf(fmaxf(s[0][r], s[1][r]), fmaxf(s[2][r], s[3][r]));
#pragma unroll
        for (int off = 1; off < 16; off <<= 1) {
#pragma unroll
            for (int r = 0; r < 4; ++r) tm[r] = fmaxf(tm[r], __shfl_xor(tm[r], off));
        }

        // ---- online softmax
        float alpha[4], ts[4];
#pragma unroll
        for (int r = 0; r < 4; ++r) {
            float mn = fmaxf(m[r], tm[r]);
            alpha[r] = __expf(m[r] - mn);
            m[r] = mn;
            ts[r] = 0.f;
        }
#pragma unroll
        for (int nt = 0; nt < 4; ++nt) {
#pragma unroll
            for (int r = 0; r < 4; ++r) {
                float p = __expf(s[nt][r] - m[r]);
                ts[r] += p;
                Psh[wv][(quad * 4 + r) * 68 + nt * 16 + l15] = (f16_t)p;
            }
        }
#pragma unroll
        for (int off = 1; off < 16; off <<= 1) {
#pragma unroll
            for (int r = 0; r < 4; ++r) ts[r] += __shfl_xor(ts[r], off);
        }
#pragma unroll
        for (int r = 0; r < 4; ++r) l[r] = l[r] * alpha[r] + ts[r];

#pragma unroll
        for (int t = 0; t < 4; ++t)
#pragma unroll
            for (int r = 0; r < 4; ++r) o[t][r] *= alpha[r];

        // ---- PV: A=P (per-wave LDS round-trip), B=V^T rows (swizzled)
#pragma unroll
        for (int kk = 0; kk < 2; ++kk) {
            f16x4 pa = *(const f16x4*)&Psh[wv][l15 * 68 + kk * 32 + quad * 8];
            f16x4 pb = *(const f16x4*)&Psh[wv][l15 * 68 + kk * 32 + quad * 8 + 4];
            f16x8 pf = __builtin_shufflevector(pa, pb, 0, 1, 2, 3, 4, 5, 6, 7);
#pragma unroll
            for (int t = 0; t < 4; ++t) {
                const int vr = t * 16 + l15;
                f16x8 vf = *(const f16x8*)&Vsh[cur][vr * 64 + (((kk * 4 + quad) ^ (l15 & 7)) << 3)];
                o[t] = __builtin_amdgcn_mfma_f32_16x16x32_f16(pf, vf, o[t], 0, 0, 0);
            }
        }

        // single barrier: (a) drains this iter's prefetch DMA (issued ~whole-iter ago),
        // (b) guarantees all waves done reading `cur` before it is overwritten next iter
        __syncthreads();
    }

    float inv[4];
#pragma unroll
    for (int r = 0; r < 4; ++r) inv[r] = 1.0f / l[r];
#pragma unroll
    for (int t = 0; t < 4; ++t) {
        int d = t * 16 + l15;
#pragma unroll
        for (int r = 0; r < 4; ++r) {
            int tok = b * SS + q0 + quad * 4 + r;
            ctx[(long)tok * DD + h * DKK + d] = (bf16_t)(o[t][r] * inv[r]);
        }
    }
}

// ---------------------------------------------------------------- launch
extern "C" void kernel_launch(void* const* d_in, const int* in_sizes, int n_in,
                              void* d_out, int out_size, void* d_ws, size_t ws_size,
                              hipStream_t stream) {
    const float* x  = (const float*)d_in[0];
    const int* mask = (const int*)d_in[1];
    const float* Wq = (const float*)d_in[2];
    const float* bq = (const float*)d_in[3];
    const float* Wk = (const float*)d_in[4];
    const float* bk = (const float*)d_in[5];
    const float* Wv = (const float*)d_in[6];
    const float* bv = (const float*)d_in[7];
    const float* Wo = (const float*)d_in[8];
    const float* bo = (const float*)d_in[9];
    float* out = (float*)d_out;

    const long NX = (long)BB * SS * DD;  // 4194304
    const long NW = (long)DD * DD;       // 1048576

    char* ws = (char*)d_ws;
    bf16_t* xh   = (bf16_t*)ws; ws += NX * 2;
    bf16_t* xl   = (bf16_t*)ws; ws += NX * 2;
    bf16_t* wqkh = (bf16_t*)ws; ws += 2 * NW * 2;
    bf16_t* wqkl = (bf16_t*)ws; ws += 2 * NW * 2;
    bf16_t* wvb  = (bf16_t*)ws; ws += NW * 2;
    bf16_t* wob  = (bf16_t*)ws; ws += NW * 2;
    f16_t*  qf   = (f16_t*)ws;  ws += NX * 2;
    f16_t*  kf   = (f16_t*)ws;  ws += NX * 2;
    f16_t*  vt   = (f16_t*)ws;  ws += NX * 2;
    bf16_t* ctx  = (bf16_t*)ws; ws += NX * 2;

    cast_split<<<2048, 256, 0, stream>>>(x, xh, xl, (int)NX);
    cast_split<<<512, 256, 0, stream>>>(Wq, wqkh, wqkl, (int)NW);
    cast_split<<<512, 256, 0, stream>>>(Wk, wqkh + NW, wqkl + NW, (int)NW);
    cast_f32_bf16<<<512, 256, 0, stream>>>(Wv, wvb, (int)NW);
    cast_f32_bf16<<<512, 256, 0, stream>>>(Wo, wob, (int)NW);

    dim3 gqk(2 * DD / 128, (BB * SS) / 128);  // (16, 32) = 512 blocks
    gemm_qk<<<gqk, 256, 0, stream>>>(xh, xl, wqkh, wqkl, bq, bk, qf, kf, DD);

    dim3 g2(DD / 128, (BB * SS) / 64);  // (8, 64) = 512 blocks
    gemm2<2><<<g2, 256, 0, stream>>>(xh, wvb, bv, nullptr, vt, DD, DD);

    dim3 agrid(SS / 64, BB * HH);  // (32, 32)
    attn_mfma3<<<agrid, 256, 0, stream>>>(qf, kf, vt, mask, ctx, SS);

    gemm2<0><<<g2, 256, 0, stream>>>(ctx, wob, bo, out, nullptr, DD, DD);
}

// Round 11
// 330.338 us; speedup vs baseline: 1.0212x; 1.0212x over previous
//
#include <hip/hip_runtime.h>
#include <hip/hip_bf16.h>
#include <math.h>

#define BB 2
#define SS 2048
#define DD 1024
#define HH 16
#define DKK 64
#define BH (BB * HH)          // 32
#define NROW (BH * SS)        // 65536 rows (bh,s)

typedef __bf16 bf16_t;
typedef _Float16 f16_t;
typedef __attribute__((ext_vector_type(8))) __bf16 bf16x8;
typedef __attribute__((ext_vector_type(4))) __bf16 bf16x4;
typedef __attribute__((ext_vector_type(8))) _Float16 f16x8;
typedef __attribute__((ext_vector_type(4))) _Float16 f16x4;
typedef __attribute__((ext_vector_type(4))) float f32x4;

// async global->LDS, 16B per lane; lds base must be wave-uniform (lane*16 implicit)
#define GLD_LDS(gp, lp) __builtin_amdgcn_global_load_lds( \
    (const __attribute__((address_space(1))) void*)(gp),  \
    (__attribute__((address_space(3))) void*)(lp), 16, 0, 0)

// ---------------------------------------------------------------- cast kernels
__global__ void cast_f32_bf16(const float* __restrict__ in, bf16_t* __restrict__ out, int n) {
    int i = blockIdx.x * blockDim.x + threadIdx.x;
    int stride = gridDim.x * blockDim.x;
    for (; i < n; i += stride) out[i] = (bf16_t)in[i];
}

__global__ void cast_split(const float* __restrict__ in, bf16_t* __restrict__ hi,
                           bf16_t* __restrict__ lo, int n) {
    int i = blockIdx.x * blockDim.x + threadIdx.x;
    int stride = gridDim.x * blockDim.x;
    for (; i < n; i += stride) {
        float v = in[i];
        bf16_t h = (bf16_t)v;
        hi[i] = h;
        lo[i] = (bf16_t)(v - (float)h);
    }
}

// ---------------------------------------------------------------- fused Q+K x3 GEMM -> fp16 split-head outputs
__global__ __launch_bounds__(256) void gemm_qk(const bf16_t* __restrict__ Ah,
                                               const bf16_t* __restrict__ Al,
                                               const bf16_t* __restrict__ Bh,
                                               const bf16_t* __restrict__ Bl,
                                               const float* __restrict__ bq,
                                               const float* __restrict__ bk,
                                               f16_t* __restrict__ q_o,
                                               f16_t* __restrict__ k_o,
                                               int K) {
    __shared__ __align__(16) bf16_t lds[16384];  // 4 chunks of 128x32
    bf16_t* sAh = lds;
    bf16_t* sAl = lds + 4096;
    bf16_t* sBh = lds + 8192;
    bf16_t* sBl = lds + 12288;

    const int tid  = threadIdx.x;
    const int wv   = tid >> 6;
    const int lane = tid & 63;
    const int quad = lane >> 4;
    const int l15  = lane & 15;
    const int wr   = wv >> 1;
    const int wc   = wv & 1;
    const int row0 = blockIdx.y * 128;
    const int col0 = blockIdx.x * 128;

    f32x4 acc[4][4] = {};

    const int srow = tid >> 2;
    const int scol = (tid & 3) * 8;
    const long aoff = (long)(row0 + srow) * K + scol;
    const long boff = (long)(col0 + srow) * K + scol;

#pragma unroll 1
    for (int kb = 0; kb < K; kb += 32) {
#pragma unroll
        for (int p = 0; p < 2; ++p) {
            const long go = (long)p * 64 * K + kb;
            const int lo = p * 2048 + wv * 512;
            GLD_LDS(Ah + aoff + go, sAh + lo);
            GLD_LDS(Al + aoff + go, sAl + lo);
            GLD_LDS(Bh + boff + go, sBh + lo);
            GLD_LDS(Bl + boff + go, sBl + lo);
        }
        __syncthreads();

        bf16x8 afh[4], afl[4];
#pragma unroll
        for (int mt = 0; mt < 4; ++mt) {
            const int ar = wr * 64 + mt * 16 + l15;
            afh[mt] = *(const bf16x8*)&sAh[ar * 32 + quad * 8];
            afl[mt] = *(const bf16x8*)&sAl[ar * 32 + quad * 8];
        }
#pragma unroll
        for (int nt = 0; nt < 4; ++nt) {
            const int br = wc * 64 + nt * 16 + l15;
            bf16x8 bh = *(const bf16x8*)&sBh[br * 32 + quad * 8];
            bf16x8 bl = *(const bf16x8*)&sBl[br * 32 + quad * 8];
#pragma unroll
            for (int mt = 0; mt < 4; ++mt) {
                acc[mt][nt] = __builtin_amdgcn_mfma_f32_16x16x32_bf16(afh[mt], bh, acc[mt][nt], 0, 0, 0);
                acc[mt][nt] = __builtin_amdgcn_mfma_f32_16x16x32_bf16(afh[mt], bl, acc[mt][nt], 0, 0, 0);
                acc[mt][nt] = __builtin_amdgcn_mfma_f32_16x16x32_bf16(afl[mt], bh, acc[mt][nt], 0, 0, 0);
            }
        }
        __syncthreads();
    }

    const bool isK = (col0 >= 1024);
    const float* bias = isK ? bk : bq;
    f16_t* op = isK ? k_o : q_o;
#pragma unroll
    for (int nt = 0; nt < 4; ++nt) {
        const int gcol = (col0 & 1023) + wc * 64 + nt * 16 + l15;
        const float bv = bias[gcol];
        const int hq = gcol >> 6, dk = gcol & 63;
#pragma unroll
        for (int mt = 0; mt < 4; ++mt) {
            const int grow0 = row0 + wr * 64 + mt * 16 + quad * 4;
#pragma unroll
            for (int r = 0; r < 4; ++r) {
                int grow = grow0 + r;
                float vv = acc[mt][nt][r] + bv;
                long off = (((long)(grow >> 11) * HH + hq) * SS + (grow & (SS - 1))) * DKK + dk;
                op[off] = (f16_t)vv;
            }
        }
    }
}

// ---------------------------------------------------------------- 64x128 GEMM (V and O projections)
// MODE 0: fp32 out[M,N]; MODE 2: fp16 V^T [B,H,DK,S]
template<int MODE>
__global__ __launch_bounds__(256) void gemm2(const bf16_t* __restrict__ Ah,
                                             const bf16_t* __restrict__ Bh,
                                             const float* __restrict__ bias,
                                             float* __restrict__ outf,
                                             f16_t* __restrict__ oh,
                                             int N, int K) {
    constexpr int ANE = 64 * 32;
    constexpr int BNE = 128 * 32;
    __shared__ __align__(16) bf16_t lds[ANE + BNE];
    bf16_t* Ash = lds;
    bf16_t* Bsh = lds + ANE;

    const int tid  = threadIdx.x;
    const int wv   = tid >> 6;
    const int lane = tid & 63;
    const int quad = lane >> 4;
    const int l15  = lane & 15;
    const int wr   = wv >> 1;
    const int wc   = wv & 1;
    const int row0 = blockIdx.y * 64;
    const int col0 = blockIdx.x * 128;

    f32x4 acc[2][4] = {};

    const int srow = lane >> 2;
    const int scol = (lane & 3) * 8;
    const bf16_t* gA  = Ah + (long)(row0 + wv * 16 + srow) * K + scol;
    const bf16_t* gB0 = Bh + (long)(col0 + wv * 16 + srow) * K + scol;
    const bf16_t* gB1 = Bh + (long)(col0 + (wv + 4) * 16 + srow) * K + scol;
    bf16_t* lA  = Ash + wv * 512;
    bf16_t* lB0 = Bsh + wv * 512;
    bf16_t* lB1 = Bsh + (wv + 4) * 512;

#pragma unroll 1
    for (int kb = 0; kb < K; kb += 32) {
        GLD_LDS(gA + kb, lA);
        GLD_LDS(gB0 + kb, lB0);
        GLD_LDS(gB1 + kb, lB1);
        __syncthreads();

        bf16x8 af[2];
#pragma unroll
        for (int mt = 0; mt < 2; ++mt)
            af[mt] = *(const bf16x8*)&Ash[(wr * 32 + mt * 16 + l15) * 32 + quad * 8];
#pragma unroll
        for (int nt = 0; nt < 4; ++nt) {
            bf16x8 bh = *(const bf16x8*)&Bsh[(wc * 64 + nt * 16 + l15) * 32 + quad * 8];
#pragma unroll
            for (int mt = 0; mt < 2; ++mt)
                acc[mt][nt] = __builtin_amdgcn_mfma_f32_16x16x32_bf16(af[mt], bh, acc[mt][nt], 0, 0, 0);
        }
        __syncthreads();
    }

#pragma unroll
    for (int mt = 0; mt < 2; ++mt) {
#pragma unroll
        for (int nt = 0; nt < 4; ++nt) {
            const int gcol  = col0 + wc * 64 + nt * 16 + l15;
            const float bv  = bias[gcol];
            const int grow0 = row0 + wr * 32 + mt * 16 + quad * 4;
            if constexpr (MODE == 0) {
#pragma unroll
                for (int r = 0; r < 4; ++r)
                    outf[(long)(grow0 + r) * N + gcol] = acc[mt][nt][r] + bv;
            } else {
                const int hq = gcol >> 6, dk = gcol & 63;
                const int bq2 = grow0 >> 11;
                const int s0  = grow0 & (SS - 1);
                f16x4 pk;
#pragma unroll
                for (int r = 0; r < 4; ++r) pk[r] = (f16_t)(acc[mt][nt][r] + bv);
                *(f16x4*)(oh + ((long)(bq2 * HH + hq) * DKK + dk) * SS + s0) = pk;
            }
        }
    }
}

// ---------------------------------------------------------------- MFMA flash attention v4: split-K partials
// v2 structure (single buffer, swizzled DMA, conflict-free) + blockIdx.z selects key half.
// Writes unnormalized partial O (fp16) + per-row (m, l); exp2-units softmax (log2e folded into Q).
__global__ __launch_bounds__(256) void attn_mfma4(const f16_t* __restrict__ Qp,
                                                  const f16_t* __restrict__ Kp,
                                                  const f16_t* __restrict__ Vtp,
                                                  const int* __restrict__ mask,
                                                  f16_t* __restrict__ Opart,
                                                  float* __restrict__ mlpart,
                                                  int klen) {
    __shared__ __align__(16) f16_t Ksh[64 * 64];     // swizzled: col-group ^ (row&7)
    __shared__ __align__(16) f16_t Vsh[64 * 64];     // swizzled V^T tile [d][key]
    __shared__ __align__(16) f16_t Psh[4][16 * 68];  // stride 68: quad banks 0/8/16/24

    const int tid  = threadIdx.x;
    const int wv   = tid >> 6;
    const int lane = tid & 63;
    const int quad = lane >> 4;
    const int l15  = lane & 15;
    const int bh   = blockIdx.y;
    const int b    = bh >> 4;
    const int kp   = blockIdx.z;
    const int q0   = blockIdx.x * 64 + wv * 16;
    const int k0   = kp * klen;

    const long kb = (long)bh * SS * DKK;  // same for Vt ([B,H,DK,S])

    // Q fragments (A-layout), pre-scaled by 8*log2(e) so scores are in exp2 units
    f16x8 qf[2];
    {
        const f16_t* pq = Qp + kb + (long)(q0 + l15) * DKK + quad * 8;
        qf[0] = *(const f16x8*)pq;
        qf[1] = *(const f16x8*)(pq + 32);
        const f16_t qs = (f16_t)(8.0f * 1.44269504088896f);
#pragma unroll
        for (int j = 0; j < 8; ++j) { qf[0][j] *= qs; qf[1][j] *= qs; }
    }

    f32x4 o[4];
    float m[4], l[4];
#pragma unroll
    for (int r = 0; r < 4; ++r) {
        o[r] = (f32x4){0.f, 0.f, 0.f, 0.f};
        m[r] = -1e30f;
        l[r] = 0.f;
    }

    const int* mrow = mask + b * SS;

    // DMA staging: inst i covers rows i*8..i*8+7; lane -> row i*8+(lane>>3),
    // stored col-group sg=lane&7 holds logical group g = sg ^ (row&7)
    const int srow8 = lane >> 3;
    const int gcolB = ((lane & 7) ^ srow8) * 8;

#pragma unroll 1
    for (int kt = k0; kt < k0 + klen; kt += 64) {
#pragma unroll
        for (int p = 0; p < 2; ++p) {
            const int i = wv * 2 + p;
            const int row = i * 8 + srow8;
            GLD_LDS(Kp + kb + (long)(kt + row) * DKK + gcolB, Ksh + i * 512);
            GLD_LDS(Vtp + kb + (long)row * SS + kt + gcolB, Vsh + i * 512);
        }
        __syncthreads();

        // ---- S = Q K^T (fp16), D[m=q=quad*4+r][n=key=nt*16+l15], exp2 units
        f32x4 s[4];
#pragma unroll
        for (int nt = 0; nt < 4; ++nt) s[nt] = (f32x4){0.f, 0.f, 0.f, 0.f};
#pragma unroll
        for (int nt = 0; nt < 4; ++nt) {
            const int kr = nt * 16 + l15;
#pragma unroll
            for (int dt = 0; dt < 2; ++dt) {
                f16x8 kf = *(const f16x8*)&Ksh[kr * 64 + (((dt * 4 + quad) ^ (l15 & 7)) << 3)];
                s[nt] = __builtin_amdgcn_mfma_f32_16x16x32_f16(qf[dt], kf, s[nt], 0, 0, 0);
            }
        }

        // ---- key-padding mask
#pragma unroll
        for (int nt = 0; nt < 4; ++nt) {
            int keep = mrow[kt + nt * 16 + l15];
#pragma unroll
            for (int r = 0; r < 4; ++r)
                s[nt][r] = keep ? s[nt][r] : -1e30f;
        }

        // ---- row max over keys
        float tm[4];
#pragma unroll
        for (int r = 0; r < 4; ++r)
            tm[r] = fmaxf(fmaxf(s[0][r], s[1][r]), fmaxf(s[2][r], s[3][r]));
#pragma unroll
        for (int off = 1; off < 16; off <<= 1) {
#pragma unroll
            for (int r = 0; r < 4; ++r) tm[r] = fmaxf(tm[r], __shfl_xor(tm[r], off));
        }

        // ---- online softmax (exp2 units)
        float alpha[4], ts[4];
#pragma unroll
        for (int r = 0; r < 4; ++r) {
            float mn = fmaxf(m[r], tm[r]);
            alpha[r] = exp2f(m[r] - mn);
            m[r] = mn;
            ts[r] = 0.f;
        }
#pragma unroll
        for (int nt = 0; nt < 4; ++nt) {
#pragma unroll
            for (int r = 0; r < 4; ++r) {
                float p = exp2f(s[nt][r] - m[r]);
                ts[r] += p;
                Psh[wv][(quad * 4 + r) * 68 + nt * 16 + l15] = (f16_t)p;
            }
        }
#pragma unroll
        for (int off = 1; off < 16; off <<= 1) {
#pragma unroll
            for (int r = 0; r < 4; ++r) ts[r] += __shfl_xor(ts[r], off);
        }
#pragma unroll
        for (int r = 0; r < 4; ++r) l[r] = l[r] * alpha[r] + ts[r];

#pragma unroll
        for (int t = 0; t < 4; ++t)
#pragma unroll
            for (int r = 0; r < 4; ++r) o[t][r] *= alpha[r];

        // ---- PV: A=P (per-wave LDS round-trip), B=V^T rows (swizzled)
#pragma unroll
        for (int kk = 0; kk < 2; ++kk) {
            f16x4 pa = *(const f16x4*)&Psh[wv][l15 * 68 + kk * 32 + quad * 8];
            f16x4 pb = *(const f16x4*)&Psh[wv][l15 * 68 + kk * 32 + quad * 8 + 4];
            f16x8 pf = __builtin_shufflevector(pa, pb, 0, 1, 2, 3, 4, 5, 6, 7);
#pragma unroll
            for (int t = 0; t < 4; ++t) {
                const int vr = t * 16 + l15;
                f16x8 vf = *(const f16x8*)&Vsh[vr * 64 + (((kk * 4 + quad) ^ (l15 & 7)) << 3)];
                o[t] = __builtin_amdgcn_mfma_f32_16x16x32_f16(pf, vf, o[t], 0, 0, 0);
            }
        }
        __syncthreads();
    }

    // ---- epilogue: write UNNORMALIZED partial O (fp16) + (m,l) per row
    const long prow0 = (long)kp * NROW + (long)bh * SS + q0 + quad * 4;
#pragma unroll
    for (int t = 0; t < 4; ++t) {
        int d = t * 16 + l15;
#pragma unroll
        for (int r = 0; r < 4; ++r)
            Opart[(prow0 + r) * DKK + d] = (f16_t)o[t][r];
    }
    if (l15 == 0) {
#pragma unroll
        for (int r = 0; r < 4; ++r) {
            mlpart[(prow0 + r) * 2 + 0] = m[r];
            mlpart[(prow0 + r) * 2 + 1] = l[r];
        }
    }
}

// ---------------------------------------------------------------- merge split-K partials -> ctx bf16
__global__ __launch_bounds__(256) void attn_merge(const f16_t* __restrict__ Opart,
                                                  const float* __restrict__ mlpart,
                                                  bf16_t* __restrict__ ctx) {
    const long idx = (long)blockIdx.x * 256 + threadIdx.x;  // over NROW*DKK
    const int d = (int)(idx & 63);
    const long row = idx >> 6;          // (bh, s)
    const int bh = (int)(row >> 11);
    const int s  = (int)(row & (SS - 1));
    const int b  = bh >> 4;
    const int h  = bh & 15;

    float m0 = mlpart[row * 2 + 0];
    float l0 = mlpart[row * 2 + 1];
    float m1 = mlpart[((long)NROW + row) * 2 + 0];
    float l1 = mlpart[((long)NROW + row) * 2 + 1];
    float M  = fmaxf(m0, m1);
    float w0 = exp2f(m0 - M);
    float w1 = exp2f(m1 - M);
    float inv = 1.0f / (l0 * w0 + l1 * w1);

    float O0 = (float)Opart[row * DKK + d];
    float O1 = (float)Opart[((long)NROW + row) * DKK + d];
    float val = (O0 * w0 + O1 * w1) * inv;

    ctx[((long)(b * SS + s)) * DD + h * DKK + d] = (bf16_t)val;
}

// ---------------------------------------------------------------- launch
extern "C" void kernel_launch(void* const* d_in, const int* in_sizes, int n_in,
                              void* d_out, int out_size, void* d_ws, size_t ws_size,
                              hipStream_t stream) {
    const float* x  = (const float*)d_in[0];
    const int* mask = (const int*)d_in[1];
    const float* Wq = (const float*)d_in[2];
    const float* bq = (const float*)d_in[3];
    const float* Wk = (const float*)d_in[4];
    const float* bk = (const float*)d_in[5];
    const float* Wv = (const float*)d_in[6];
    const float* bv = (const float*)d_in[7];
    const float* Wo = (const float*)d_in[8];
    const float* bo = (const float*)d_in[9];
    float* out = (float*)d_out;

    const long NX = (long)BB * SS * DD;  // 4194304
    const long NW = (long)DD * DD;       // 1048576

    char* ws = (char*)d_ws;
    bf16_t* xh   = (bf16_t*)ws; ws += NX * 2;
    bf16_t* xl   = (bf16_t*)ws; ws += NX * 2;
    bf16_t* wqkh = (bf16_t*)ws; ws += 2 * NW * 2;
    bf16_t* wqkl = (bf16_t*)ws; ws += 2 * NW * 2;
    bf16_t* wvb  = (bf16_t*)ws; ws += NW * 2;
    bf16_t* wob  = (bf16_t*)ws; ws += NW * 2;
    f16_t*  qf   = (f16_t*)ws;  ws += NX * 2;
    f16_t*  kf   = (f16_t*)ws;  ws += NX * 2;
    f16_t*  vt   = (f16_t*)ws;  ws += NX * 2;
    bf16_t* ctx  = (bf16_t*)ws; ws += NX * 2;
    f16_t*  Opart = (f16_t*)ws; ws += 2 * NX * 2;          // [2][BH,S,DK] fp16
    float*  mlp   = (float*)ws; ws += 2L * NROW * 2 * 4;   // [2][NROW][m,l]

    cast_split<<<2048, 256, 0, stream>>>(x, xh, xl, (int)NX);
    cast_split<<<512, 256, 0, stream>>>(Wq, wqkh, wqkl, (int)NW);
    cast_split<<<512, 256, 0, stream>>>(Wk, wqkh + NW, wqkl + NW, (int)NW);
    cast_f32_bf16<<<512, 256, 0, stream>>>(Wv, wvb, (int)NW);
    cast_f32_bf16<<<512, 256, 0, stream>>>(Wo, wob, (int)NW);

    dim3 gqk(2 * DD / 128, (BB * SS) / 128);  // (16, 32) = 512 blocks
    gemm_qk<<<gqk, 256, 0, stream>>>(xh, xl, wqkh, wqkl, bq, bk, qf, kf, DD);

    dim3 g2(DD / 128, (BB * SS) / 64);  // (8, 64) = 512 blocks
    gemm2<2><<<g2, 256, 0, stream>>>(xh, wvb, bv, nullptr, vt, DD, DD);

    dim3 agrid(SS / 64, BH, 2);  // (32, 32, 2) = 2048 blocks
    attn_mfma4<<<agrid, 256, 0, stream>>>(qf, kf, vt, mask, Opart, mlp, SS / 2);

    attn_merge<<<(int)((long)NROW * DKK / 256), 256, 0, stream>>>(Opart, mlp, ctx);

    gemm2<0><<<g2, 256, 0, stream>>>(ctx, wob, bo, out, nullptr, DD, DD);
}

// Round 12
// 305.648 us; speedup vs baseline: 1.1037x; 1.0808x over previous
//
#include <hip/hip_runtime.h>
#include <hip/hip_bf16.h>
#include <math.h>

#define BB 2
#define SS 2048
#define DD 1024
#define HH 16
#define DKK 64
#define BH (BB * HH)          // 32

typedef __bf16 bf16_t;
typedef _Float16 f16_t;
typedef __attribute__((ext_vector_type(8))) __bf16 bf16x8;
typedef __attribute__((ext_vector_type(4))) __bf16 bf16x4;
typedef __attribute__((ext_vector_type(8))) _Float16 f16x8;
typedef __attribute__((ext_vector_type(4))) _Float16 f16x4;
typedef __attribute__((ext_vector_type(4))) float f32x4;

// async global->LDS, 16B per lane; lds base must be wave-uniform (lane*16 implicit)
#define GLD_LDS(gp, lp) __builtin_amdgcn_global_load_lds( \
    (const __attribute__((address_space(1))) void*)(gp),  \
    (__attribute__((address_space(3))) void*)(lp), 16, 0, 0)

// ---------------------------------------------------------------- cast kernels
__global__ void cast_f32_bf16(const float* __restrict__ in, bf16_t* __restrict__ out, int n) {
    int i = blockIdx.x * blockDim.x + threadIdx.x;
    int stride = gridDim.x * blockDim.x;
    for (; i < n; i += stride) out[i] = (bf16_t)in[i];
}

__global__ void cast_split(const float* __restrict__ in, bf16_t* __restrict__ hi,
                           bf16_t* __restrict__ lo, int n) {
    int i = blockIdx.x * blockDim.x + threadIdx.x;
    int stride = gridDim.x * blockDim.x;
    for (; i < n; i += stride) {
        float v = in[i];
        bf16_t h = (bf16_t)v;
        hi[i] = h;
        lo[i] = (bf16_t)(v - (float)h);
    }
}

// all-keep flags per (b, 128-key block)
__global__ void mask_flags(const int* __restrict__ mask, int* __restrict__ flags) {
    int f = threadIdx.x;
    if (f < BB * (SS / 128)) {
        int b = f / (SS / 128), t = f % (SS / 128);
        const int* p = mask + b * SS + t * 128;
        int all = 1;
        for (int i = 0; i < 128; ++i) all &= (p[i] != 0);
        flags[f] = all;
    }
}

// ---------------------------------------------------------------- fused Q+K x3 GEMM -> fp16 split-head outputs
__global__ __launch_bounds__(256) void gemm_qk(const bf16_t* __restrict__ Ah,
                                               const bf16_t* __restrict__ Al,
                                               const bf16_t* __restrict__ Bh,
                                               const bf16_t* __restrict__ Bl,
                                               const float* __restrict__ bq,
                                               const float* __restrict__ bk,
                                               f16_t* __restrict__ q_o,
                                               f16_t* __restrict__ k_o,
                                               int K) {
    __shared__ __align__(16) bf16_t lds[16384];  // 4 chunks of 128x32
    bf16_t* sAh = lds;
    bf16_t* sAl = lds + 4096;
    bf16_t* sBh = lds + 8192;
    bf16_t* sBl = lds + 12288;

    const int tid  = threadIdx.x;
    const int wv   = tid >> 6;
    const int lane = tid & 63;
    const int quad = lane >> 4;
    const int l15  = lane & 15;
    const int wr   = wv >> 1;
    const int wc   = wv & 1;
    const int row0 = blockIdx.y * 128;
    const int col0 = blockIdx.x * 128;

    f32x4 acc[4][4] = {};

    const int srow = tid >> 2;
    const int scol = (tid & 3) * 8;
    const long aoff = (long)(row0 + srow) * K + scol;
    const long boff = (long)(col0 + srow) * K + scol;

#pragma unroll 1
    for (int kb = 0; kb < K; kb += 32) {
#pragma unroll
        for (int p = 0; p < 2; ++p) {
            const long go = (long)p * 64 * K + kb;
            const int lo = p * 2048 + wv * 512;
            GLD_LDS(Ah + aoff + go, sAh + lo);
            GLD_LDS(Al + aoff + go, sAl + lo);
            GLD_LDS(Bh + boff + go, sBh + lo);
            GLD_LDS(Bl + boff + go, sBl + lo);
        }
        __syncthreads();

        bf16x8 afh[4], afl[4];
#pragma unroll
        for (int mt = 0; mt < 4; ++mt) {
            const int ar = wr * 64 + mt * 16 + l15;
            afh[mt] = *(const bf16x8*)&sAh[ar * 32 + quad * 8];
            afl[mt] = *(const bf16x8*)&sAl[ar * 32 + quad * 8];
        }
#pragma unroll
        for (int nt = 0; nt < 4; ++nt) {
            const int br = wc * 64 + nt * 16 + l15;
            bf16x8 bh = *(const bf16x8*)&sBh[br * 32 + quad * 8];
            bf16x8 bl = *(const bf16x8*)&sBl[br * 32 + quad * 8];
#pragma unroll
            for (int mt = 0; mt < 4; ++mt) {
                acc[mt][nt] = __builtin_amdgcn_mfma_f32_16x16x32_bf16(afh[mt], bh, acc[mt][nt], 0, 0, 0);
                acc[mt][nt] = __builtin_amdgcn_mfma_f32_16x16x32_bf16(afh[mt], bl, acc[mt][nt], 0, 0, 0);
                acc[mt][nt] = __builtin_amdgcn_mfma_f32_16x16x32_bf16(afl[mt], bh, acc[mt][nt], 0, 0, 0);
            }
        }
        __syncthreads();
    }

    const bool isK = (col0 >= 1024);
    const float* bias = isK ? bk : bq;
    f16_t* op = isK ? k_o : q_o;
#pragma unroll
    for (int nt = 0; nt < 4; ++nt) {
        const int gcol = (col0 & 1023) + wc * 64 + nt * 16 + l15;
        const float bv = bias[gcol];
        const int hq = gcol >> 6, dk = gcol & 63;
#pragma unroll
        for (int mt = 0; mt < 4; ++mt) {
            const int grow0 = row0 + wr * 64 + mt * 16 + quad * 4;
#pragma unroll
            for (int r = 0; r < 4; ++r) {
                int grow = grow0 + r;
                float vv = acc[mt][nt][r] + bv;
                long off = (((long)(grow >> 11) * HH + hq) * SS + (grow & (SS - 1))) * DKK + dk;
                op[off] = (f16_t)vv;
            }
        }
    }
}

// ---------------------------------------------------------------- 64x128 GEMM (V and O projections)
// MODE 0: fp32 out[M,N]; MODE 2: fp16 V^T [B,H,DK,S]
template<int MODE>
__global__ __launch_bounds__(256) void gemm2(const bf16_t* __restrict__ Ah,
                                             const bf16_t* __restrict__ Bh,
                                             const float* __restrict__ bias,
                                             float* __restrict__ outf,
                                             f16_t* __restrict__ oh,
                                             int N, int K) {
    constexpr int ANE = 64 * 32;
    constexpr int BNE = 128 * 32;
    __shared__ __align__(16) bf16_t lds[ANE + BNE];
    bf16_t* Ash = lds;
    bf16_t* Bsh = lds + ANE;

    const int tid  = threadIdx.x;
    const int wv   = tid >> 6;
    const int lane = tid & 63;
    const int quad = lane >> 4;
    const int l15  = lane & 15;
    const int wr   = wv >> 1;
    const int wc   = wv & 1;
    const int row0 = blockIdx.y * 64;
    const int col0 = blockIdx.x * 128;

    f32x4 acc[2][4] = {};

    const int srow = lane >> 2;
    const int scol = (lane & 3) * 8;
    const bf16_t* gA  = Ah + (long)(row0 + wv * 16 + srow) * K + scol;
    const bf16_t* gB0 = Bh + (long)(col0 + wv * 16 + srow) * K + scol;
    const bf16_t* gB1 = Bh + (long)(col0 + (wv + 4) * 16 + srow) * K + scol;
    bf16_t* lA  = Ash + wv * 512;
    bf16_t* lB0 = Bsh + wv * 512;
    bf16_t* lB1 = Bsh + (wv + 4) * 512;

#pragma unroll 1
    for (int kb = 0; kb < K; kb += 32) {
        GLD_LDS(gA + kb, lA);
        GLD_LDS(gB0 + kb, lB0);
        GLD_LDS(gB1 + kb, lB1);
        __syncthreads();

        bf16x8 af[2];
#pragma unroll
        for (int mt = 0; mt < 2; ++mt)
            af[mt] = *(const bf16x8*)&Ash[(wr * 32 + mt * 16 + l15) * 32 + quad * 8];
#pragma unroll
        for (int nt = 0; nt < 4; ++nt) {
            bf16x8 bh = *(const bf16x8*)&Bsh[(wc * 64 + nt * 16 + l15) * 32 + quad * 8];
#pragma unroll
            for (int mt = 0; mt < 2; ++mt)
                acc[mt][nt] = __builtin_amdgcn_mfma_f32_16x16x32_bf16(af[mt], bh, acc[mt][nt], 0, 0, 0);
        }
        __syncthreads();
    }

#pragma unroll
    for (int mt = 0; mt < 2; ++mt) {
#pragma unroll
        for (int nt = 0; nt < 4; ++nt) {
            const int gcol  = col0 + wc * 64 + nt * 16 + l15;
            const float bv  = bias[gcol];
            const int grow0 = row0 + wr * 32 + mt * 16 + quad * 4;
            if constexpr (MODE == 0) {
#pragma unroll
                for (int r = 0; r < 4; ++r)
                    outf[(long)(grow0 + r) * N + gcol] = acc[mt][nt][r] + bv;
            } else {
                const int hq = gcol >> 6, dk = gcol & 63;
                const int bq2 = grow0 >> 11;
                const int s0  = grow0 & (SS - 1);
                f16x4 pk;
#pragma unroll
                for (int r = 0; r < 4; ++r) pk[r] = (f16_t)(acc[mt][nt][r] + bv);
                *(f16x4*)(oh + ((long)(bq2 * HH + hq) * DKK + dk) * SS + s0) = pk;
            }
        }
    }
}

// ---------------------------------------------------------------- MFMA flash attention v5
// 128-key tiles (2 x verified 64-key sub-tile layout), single-buffered, fp16,
// ones-column MFMA computes l (no shuffle-reduce), mask fast-path, exp2 softmax.
__global__ __launch_bounds__(256) void attn_mfma5(const f16_t* __restrict__ Qp,
                                                  const f16_t* __restrict__ Kp,
                                                  const f16_t* __restrict__ Vtp,
                                                  const int* __restrict__ mask,
                                                  const int* __restrict__ flags,
                                                  bf16_t* __restrict__ ctx,
                                                  int seq_len) {
    __shared__ __align__(16) f16_t Ksh[2][4096];      // 2 sub-tiles, swizzled col-group ^ (row&7)
    __shared__ __align__(16) f16_t Vsh[2][4096];      // 2 sub-tiles of V^T [d][key]
    __shared__ __align__(16) f16_t Psh[4][16 * 132];  // stride 132: conflict-free stores

    const int tid  = threadIdx.x;
    const int wv   = tid >> 6;
    const int lane = tid & 63;
    const int quad = lane >> 4;
    const int l15  = lane & 15;
    const int bh   = blockIdx.y;
    const int b    = bh >> 4;
    const int h    = bh & 15;
    const int q0   = blockIdx.x * 64 + wv * 16;

    const long kb = (long)bh * SS * DKK;  // same for Vt ([B,H,DK,S])

    // Q fragments (A-layout), pre-scaled by 8*log2(e): scores in exp2 units
    f16x8 qf[2];
    {
        const f16_t* pq = Qp + kb + (long)(q0 + l15) * DKK + quad * 8;
        qf[0] = *(const f16x8*)pq;
        qf[1] = *(const f16x8*)(pq + 32);
        const f16_t qs = (f16_t)(8.0f * 1.44269504088896f);
#pragma unroll
        for (int j = 0; j < 8; ++j) { qf[0][j] *= qs; qf[1][j] *= qs; }
    }

    f16x8 ones;
#pragma unroll
    for (int j = 0; j < 8; ++j) ones[j] = (f16_t)1.0f;

    f32x4 o[4], lacc;
    float m[4];
#pragma unroll
    for (int r = 0; r < 4; ++r) {
        o[r] = (f32x4){0.f, 0.f, 0.f, 0.f};
        m[r] = -1e30f;
    }
    lacc = (f32x4){0.f, 0.f, 0.f, 0.f};

    const int* mrow = mask + b * SS;
    const int* frow = flags + b * (SS / 128);

    // DMA staging (per 64-key sub-tile, v2-verified): inst i covers rows i*8..i*8+7
    const int srow8 = lane >> 3;
    const int gcolB = ((lane & 7) ^ srow8) * 8;

#pragma unroll 1
    for (int kt = 0; kt < seq_len; kt += 128) {
#pragma unroll
        for (int c = 0; c < 2; ++c) {
            const int kc = kt + c * 64;
#pragma unroll
            for (int p = 0; p < 2; ++p) {
                const int i = wv * 2 + p;
                const int row = i * 8 + srow8;
                GLD_LDS(Kp + kb + (long)(kc + row) * DKK + gcolB, &Ksh[c][i * 512]);
                GLD_LDS(Vtp + kb + (long)row * SS + kc + gcolB, &Vsh[c][i * 512]);
            }
        }
        __syncthreads();

        // ---- S = Q K^T over 128 keys, D[m=q=quad*4+r][n=key=nt*16+l15]
        f32x4 s[8];
#pragma unroll
        for (int nt = 0; nt < 8; ++nt) s[nt] = (f32x4){0.f, 0.f, 0.f, 0.f};
#pragma unroll
        for (int nt = 0; nt < 8; ++nt) {
            const int c = nt >> 2;
            const int kr = (nt & 3) * 16 + l15;
#pragma unroll
            for (int dt = 0; dt < 2; ++dt) {
                f16x8 kf = *(const f16x8*)&Ksh[c][kr * 64 + (((dt * 4 + quad) ^ (l15 & 7)) << 3)];
                s[nt] = __builtin_amdgcn_mfma_f32_16x16x32_f16(qf[dt], kf, s[nt], 0, 0, 0);
            }
        }

        // ---- key-padding mask (fast path: wave-uniform skip when tile all-keep)
        if (!frow[kt >> 7]) {
#pragma unroll
            for (int nt = 0; nt < 8; ++nt) {
                int keep = mrow[kt + nt * 16 + l15];
#pragma unroll
                for (int r = 0; r < 4; ++r)
                    s[nt][r] = keep ? s[nt][r] : -1e30f;
            }
        }

        // ---- row max over 128 keys
        float tm[4];
#pragma unroll
        for (int r = 0; r < 4; ++r) {
            tm[r] = fmaxf(fmaxf(fmaxf(s[0][r], s[1][r]), fmaxf(s[2][r], s[3][r])),
                          fmaxf(fmaxf(s[4][r], s[5][r]), fmaxf(s[6][r], s[7][r])));
        }
#pragma unroll
        for (int off = 1; off < 16; off <<= 1) {
#pragma unroll
            for (int r = 0; r < 4; ++r) tm[r] = fmaxf(tm[r], __shfl_xor(tm[r], off));
        }

        // ---- online softmax scale factors
        float alpha[4];
#pragma unroll
        for (int r = 0; r < 4; ++r) {
            float mn = fmaxf(m[r], tm[r]);
            alpha[r] = exp2f(m[r] - mn);
            m[r] = mn;
        }

        // ---- p = exp2(s - m) -> Psh (fp16)
#pragma unroll
        for (int nt = 0; nt < 8; ++nt) {
#pragma unroll
            for (int r = 0; r < 4; ++r) {
                float p = exp2f(s[nt][r] - m[r]);
                Psh[wv][(quad * 4 + r) * 132 + nt * 16 + l15] = (f16_t)p;
            }
        }

        // ---- rescale O and l-accumulator
#pragma unroll
        for (int t = 0; t < 4; ++t)
#pragma unroll
            for (int r = 0; r < 4; ++r) o[t][r] *= alpha[r];
#pragma unroll
        for (int r = 0; r < 4; ++r) lacc[r] *= alpha[r];

        // ---- PV + ones-column (l): A=P, B=V^T rows / ones
#pragma unroll
        for (int kk = 0; kk < 4; ++kk) {
            const int c = kk >> 1;
            const int kk2 = kk & 1;
            f16x4 pa = *(const f16x4*)&Psh[wv][l15 * 132 + kk * 32 + quad * 8];
            f16x4 pb = *(const f16x4*)&Psh[wv][l15 * 132 + kk * 32 + quad * 8 + 4];
            f16x8 pf = __builtin_shufflevector(pa, pb, 0, 1, 2, 3, 4, 5, 6, 7);
#pragma unroll
            for (int t = 0; t < 4; ++t) {
                const int vr = t * 16 + l15;
                f16x8 vf = *(const f16x8*)&Vsh[c][vr * 64 + (((kk2 * 4 + quad) ^ (l15 & 7)) << 3)];
                o[t] = __builtin_amdgcn_mfma_f32_16x16x32_f16(pf, vf, o[t], 0, 0, 0);
            }
            lacc = __builtin_amdgcn_mfma_f32_16x16x32_f16(pf, ones, lacc, 0, 0, 0);
        }
        __syncthreads();
    }

    // ---- epilogue: l = lacc (same value in every lane's n-column), normalize, write ctx
    float inv[4];
#pragma unroll
    for (int r = 0; r < 4; ++r) inv[r] = 1.0f / lacc[r];
#pragma unroll
    for (int t = 0; t < 4; ++t) {
        int d = t * 16 + l15;
#pragma unroll
        for (int r = 0; r < 4; ++r) {
            int tok = b * SS + q0 + quad * 4 + r;
            ctx[(long)tok * DD + h * DKK + d] = (bf16_t)(o[t][r] * inv[r]);
        }
    }
}

// ---------------------------------------------------------------- launch
extern "C" void kernel_launch(void* const* d_in, const int* in_sizes, int n_in,
                              void* d_out, int out_size, void* d_ws, size_t ws_size,
                              hipStream_t stream) {
    const float* x  = (const float*)d_in[0];
    const int* mask = (const int*)d_in[1];
    const float* Wq = (const float*)d_in[2];
    const float* bq = (const float*)d_in[3];
    const float* Wk = (const float*)d_in[4];
    const float* bk = (const float*)d_in[5];
    const float* Wv = (const float*)d_in[6];
    const float* bv = (const float*)d_in[7];
    const float* Wo = (const float*)d_in[8];
    const float* bo = (const float*)d_in[9];
    float* out = (float*)d_out;

    const long NX = (long)BB * SS * DD;  // 4194304
    const long NW = (long)DD * DD;       // 1048576

    char* ws = (char*)d_ws;
    bf16_t* xh   = (bf16_t*)ws; ws += NX * 2;
    bf16_t* xl   = (bf16_t*)ws; ws += NX * 2;
    bf16_t* wqkh = (bf16_t*)ws; ws += 2 * NW * 2;
    bf16_t* wqkl = (bf16_t*)ws; ws += 2 * NW * 2;
    bf16_t* wvb  = (bf16_t*)ws; ws += NW * 2;
    bf16_t* wob  = (bf16_t*)ws; ws += NW * 2;
    f16_t*  qf   = (f16_t*)ws;  ws += NX * 2;
    f16_t*  kf   = (f16_t*)ws;  ws += NX * 2;
    f16_t*  vt   = (f16_t*)ws;  ws += NX * 2;
    bf16_t* ctx  = (bf16_t*)ws; ws += NX * 2;
    int*    flg  = (int*)ws;    ws += 64 * 4;

    cast_split<<<2048, 256, 0, stream>>>(x, xh, xl, (int)NX);
    cast_split<<<512, 256, 0, stream>>>(Wq, wqkh, wqkl, (int)NW);
    cast_split<<<512, 256, 0, stream>>>(Wk, wqkh + NW, wqkl + NW, (int)NW);
    cast_f32_bf16<<<512, 256, 0, stream>>>(Wv, wvb, (int)NW);
    cast_f32_bf16<<<512, 256, 0, stream>>>(Wo, wob, (int)NW);
    mask_flags<<<1, 64, 0, stream>>>(mask, flg);

    dim3 gqk(2 * DD / 128, (BB * SS) / 128);  // (16, 32) = 512 blocks
    gemm_qk<<<gqk, 256, 0, stream>>>(xh, xl, wqkh, wqkl, bq, bk, qf, kf, DD);

    dim3 g2(DD / 128, (BB * SS) / 64);  // (8, 64) = 512 blocks
    gemm2<2><<<g2, 256, 0, stream>>>(xh, wvb, bv, nullptr, vt, DD, DD);

    dim3 agrid(SS / 64, BH);  // (32, 32) = 1024 blocks
    attn_mfma5<<<agrid, 256, 0, stream>>>(qf, kf, vt, mask, flg, ctx, SS);

    gemm2<0><<<g2, 256, 0, stream>>>(ctx, wob, bo, out, nullptr, DD, DD);
}

// Round 13
// 283.734 us; speedup vs baseline: 1.1889x; 1.0772x over previous
//
#include <hip/hip_runtime.h>
#include <hip/hip_bf16.h>
#include <math.h>

#define BB 2
#define SS 2048
#define DD 1024
#define HH 16
#define DKK 64
#define BH (BB * HH)          // 32

typedef __bf16 bf16_t;
typedef _Float16 f16_t;
typedef __attribute__((ext_vector_type(8))) _Float16 f16x8;
typedef __attribute__((ext_vector_type(4))) _Float16 f16x4;
typedef __attribute__((ext_vector_type(4))) float f32x4;

// async global->LDS, 16B per lane; lds base must be wave-uniform (lane*16 implicit)
#define GLD_LDS(gp, lp) __builtin_amdgcn_global_load_lds( \
    (const __attribute__((address_space(1))) void*)(gp),  \
    (__attribute__((address_space(3))) void*)(lp), 16, 0, 0)

// ---------------------------------------------------------------- prep kernels
// x -> fp16, plus per-(b,128-key-block) all-keep flags
__global__ void cast_x_flags(const float* __restrict__ in, f16_t* __restrict__ out,
                             const int* __restrict__ mask, int* __restrict__ flags, int n) {
    int i = blockIdx.x * blockDim.x + threadIdx.x;
    int stride = gridDim.x * blockDim.x;
    for (; i < n; i += stride) out[i] = (f16_t)in[i];
    if (blockIdx.x == 0 && threadIdx.x < BB * (SS / 128)) {
        int f = threadIdx.x;
        int b = f / (SS / 128), t = f % (SS / 128);
        const int* p = mask + b * SS + t * 128;
        int all = 1;
        for (int j = 0; j < 128; ++j) all &= (p[j] != 0);
        flags[f] = all;
    }
}

// [Wq;Wk] -> fused fp16 hi + fp16 lo (lo = residual; may be subnormal)
__global__ void cast_wqk(const float* __restrict__ Wq, const float* __restrict__ Wk,
                         f16_t* __restrict__ hi, f16_t* __restrict__ lo, int nw) {
    int i = blockIdx.x * blockDim.x + threadIdx.x;
    int stride = gridDim.x * blockDim.x;
    for (; i < 2 * nw; i += stride) {
        float v = (i < nw) ? Wq[i] : Wk[i - nw];
        f16_t h = (f16_t)v;
        hi[i] = h;
        lo[i] = (f16_t)(v - (float)h);
    }
}

// Wv, Wo -> fp16
__global__ void cast_wvo(const float* __restrict__ Wv, const float* __restrict__ Wo,
                         f16_t* __restrict__ wv, f16_t* __restrict__ wo, int nw) {
    int i = blockIdx.x * blockDim.x + threadIdx.x;
    int stride = gridDim.x * blockDim.x;
    for (; i < 2 * nw; i += stride) {
        if (i < nw) wv[i] = (f16_t)Wv[i];
        else        wo[i - nw] = (f16_t)Wo[i - nw];
    }
}

// ---------------------------------------------------------------- fused QKV GEMM (fp16)
// A = x_f16 [4096,1024]. Columns: [0,2048) = [Wq;Wk] fp16 hi/lo (2 MFMAs);
// [2048,3072) = Wv fp16 (1 MFMA). Tile 128x128, BK=32, 4 waves 2x2, 4x4 accs.
// Outputs: q/k fp16 split-head [B,H,S,DK]; v fp16 V^T [B,H,DK,S].
__global__ __launch_bounds__(256) void gemm_qkv(const f16_t* __restrict__ Af,
                                                const f16_t* __restrict__ Wqkh,
                                                const f16_t* __restrict__ Wqkl,
                                                const f16_t* __restrict__ Wvf,
                                                const float* __restrict__ bq,
                                                const float* __restrict__ bk,
                                                const float* __restrict__ bv,
                                                f16_t* __restrict__ q_o,
                                                f16_t* __restrict__ k_o,
                                                f16_t* __restrict__ vt_o,
                                                int K) {
    __shared__ __align__(16) f16_t sA[4096];
    __shared__ __align__(16) f16_t sB0[4096];
    __shared__ __align__(16) f16_t sB1[4096];

    const int tid  = threadIdx.x;
    const int wv   = tid >> 6;
    const int lane = tid & 63;
    const int quad = lane >> 4;
    const int l15  = lane & 15;
    const int wr   = wv >> 1;
    const int wc   = wv & 1;
    const int row0 = blockIdx.y * 128;
    const int col0 = blockIdx.x * 128;
    const bool isV = (col0 >= 2048);

    const f16_t* B0 = isV ? (Wvf + (long)(col0 - 2048) * K) : (Wqkh + (long)col0 * K);
    const f16_t* B1 = isV ? nullptr : (Wqkl + (long)col0 * K);

    f32x4 acc[4][4] = {};

    const int srow = tid >> 2;
    const int scol = (tid & 3) * 8;
    const long aoff = (long)(row0 + srow) * K + scol;
    const long boff = (long)srow * K + scol;

    if (isV) {
#pragma unroll 1
        for (int kb = 0; kb < K; kb += 32) {
#pragma unroll
            for (int p = 0; p < 2; ++p) {
                const long go = (long)p * 64 * K + kb;
                const int lo = p * 2048 + wv * 512;
                GLD_LDS(Af + aoff + go, sA + lo);
                GLD_LDS(B0 + boff + go, sB0 + lo);
            }
            __syncthreads();
            f16x8 af[4];
#pragma unroll
            for (int mt = 0; mt < 4; ++mt)
                af[mt] = *(const f16x8*)&sA[(wr * 64 + mt * 16 + l15) * 32 + quad * 8];
#pragma unroll
            for (int nt = 0; nt < 4; ++nt) {
                f16x8 b0 = *(const f16x8*)&sB0[(wc * 64 + nt * 16 + l15) * 32 + quad * 8];
#pragma unroll
                for (int mt = 0; mt < 4; ++mt)
                    acc[mt][nt] = __builtin_amdgcn_mfma_f32_16x16x32_f16(af[mt], b0, acc[mt][nt], 0, 0, 0);
            }
            __syncthreads();
        }
    } else {
#pragma unroll 1
        for (int kb = 0; kb < K; kb += 32) {
#pragma unroll
            for (int p = 0; p < 2; ++p) {
                const long go = (long)p * 64 * K + kb;
                const int lo = p * 2048 + wv * 512;
                GLD_LDS(Af + aoff + go, sA + lo);
                GLD_LDS(B0 + boff + go, sB0 + lo);
                GLD_LDS(B1 + boff + go, sB1 + lo);
            }
            __syncthreads();
            f16x8 af[4];
#pragma unroll
            for (int mt = 0; mt < 4; ++mt)
                af[mt] = *(const f16x8*)&sA[(wr * 64 + mt * 16 + l15) * 32 + quad * 8];
#pragma unroll
            for (int nt = 0; nt < 4; ++nt) {
                f16x8 b0 = *(const f16x8*)&sB0[(wc * 64 + nt * 16 + l15) * 32 + quad * 8];
                f16x8 b1 = *(const f16x8*)&sB1[(wc * 64 + nt * 16 + l15) * 32 + quad * 8];
#pragma unroll
                for (int mt = 0; mt < 4; ++mt) {
                    acc[mt][nt] = __builtin_amdgcn_mfma_f32_16x16x32_f16(af[mt], b0, acc[mt][nt], 0, 0, 0);
                    acc[mt][nt] = __builtin_amdgcn_mfma_f32_16x16x32_f16(af[mt], b1, acc[mt][nt], 0, 0, 0);
                }
            }
            __syncthreads();
        }
    }

    if (isV) {
        // V^T epilogue: vt[((b*H+h)*DK+dk)*S + s], 4 consecutive s per lane
#pragma unroll
        for (int nt = 0; nt < 4; ++nt) {
            const int colv = (col0 - 2048) + wc * 64 + nt * 16 + l15;  // [0,1024)
            const float bvv = bv[colv];
            const int hq = colv >> 6, dk = colv & 63;
#pragma unroll
            for (int mt = 0; mt < 4; ++mt) {
                const int grow0 = row0 + wr * 64 + mt * 16 + quad * 4;
                const int bq2 = grow0 >> 11;
                const int s0  = grow0 & (SS - 1);
                f16x4 pk;
#pragma unroll
                for (int r = 0; r < 4; ++r) pk[r] = (f16_t)(acc[mt][nt][r] + bvv);
                *(f16x4*)(vt_o + ((long)(bq2 * HH + hq) * DKK + dk) * SS + s0) = pk;
            }
        }
    } else {
        const bool isK = (col0 >= 1024);
        const float* bias = isK ? bk : bq;
        f16_t* op = isK ? k_o : q_o;
#pragma unroll
        for (int nt = 0; nt < 4; ++nt) {
            const int gcol = (col0 & 1023) + wc * 64 + nt * 16 + l15;
            const float bvv = bias[gcol];
            const int hq = gcol >> 6, dk = gcol & 63;
#pragma unroll
            for (int mt = 0; mt < 4; ++mt) {
                const int grow0 = row0 + wr * 64 + mt * 16 + quad * 4;
#pragma unroll
                for (int r = 0; r < 4; ++r) {
                    int grow = grow0 + r;
                    float vvv = acc[mt][nt][r] + bvv;
                    long off = (((long)(grow >> 11) * HH + hq) * SS + (grow & (SS - 1))) * DKK + dk;
                    op[off] = (f16_t)vvv;
                }
            }
        }
    }
}

// ---------------------------------------------------------------- O-projection GEMM (fp16 in, fp32 out)
// A = ctx f16 [M,K]; B = Wo f16 [N,K]; out fp32 [M,N]. Tile 64x128, BK=32.
__global__ __launch_bounds__(256) void gemm_o(const f16_t* __restrict__ Ah,
                                              const f16_t* __restrict__ Bhp,
                                              const float* __restrict__ bias,
                                              float* __restrict__ outf,
                                              int N, int K) {
    __shared__ __align__(16) f16_t lds[2048 + 4096];
    f16_t* Ash = lds;
    f16_t* Bsh = lds + 2048;

    const int tid  = threadIdx.x;
    const int wv   = tid >> 6;
    const int lane = tid & 63;
    const int quad = lane >> 4;
    const int l15  = lane & 15;
    const int wr   = wv >> 1;
    const int wc   = wv & 1;
    const int row0 = blockIdx.y * 64;
    const int col0 = blockIdx.x * 128;

    f32x4 acc[2][4] = {};

    const int srow = lane >> 2;
    const int scol = (lane & 3) * 8;
    const f16_t* gA  = Ah  + (long)(row0 + wv * 16 + srow) * K + scol;
    const f16_t* gB0 = Bhp + (long)(col0 + wv * 16 + srow) * K + scol;
    const f16_t* gB1 = Bhp + (long)(col0 + (wv + 4) * 16 + srow) * K + scol;
    f16_t* lA  = Ash + wv * 512;
    f16_t* lB0 = Bsh + wv * 512;
    f16_t* lB1 = Bsh + (wv + 4) * 512;

#pragma unroll 1
    for (int kb = 0; kb < K; kb += 32) {
        GLD_LDS(gA + kb, lA);
        GLD_LDS(gB0 + kb, lB0);
        GLD_LDS(gB1 + kb, lB1);
        __syncthreads();

        f16x8 af[2];
#pragma unroll
        for (int mt = 0; mt < 2; ++mt)
            af[mt] = *(const f16x8*)&Ash[(wr * 32 + mt * 16 + l15) * 32 + quad * 8];
#pragma unroll
        for (int nt = 0; nt < 4; ++nt) {
            f16x8 bh = *(const f16x8*)&Bsh[(wc * 64 + nt * 16 + l15) * 32 + quad * 8];
#pragma unroll
            for (int mt = 0; mt < 2; ++mt)
                acc[mt][nt] = __builtin_amdgcn_mfma_f32_16x16x32_f16(af[mt], bh, acc[mt][nt], 0, 0, 0);
        }
        __syncthreads();
    }

#pragma unroll
    for (int mt = 0; mt < 2; ++mt) {
#pragma unroll
        for (int nt = 0; nt < 4; ++nt) {
            const int gcol  = col0 + wc * 64 + nt * 16 + l15;
            const float bvv = bias[gcol];
            const int grow0 = row0 + wr * 32 + mt * 16 + quad * 4;
#pragma unroll
            for (int r = 0; r < 4; ++r)
                outf[(long)(grow0 + r) * N + gcol] = acc[mt][nt][r] + bvv;
        }
    }
}

// ---------------------------------------------------------------- MFMA flash attention v5 (unchanged; ctx fp16)
__global__ __launch_bounds__(256) void attn_mfma5(const f16_t* __restrict__ Qp,
                                                  const f16_t* __restrict__ Kp,
                                                  const f16_t* __restrict__ Vtp,
                                                  const int* __restrict__ mask,
                                                  const int* __restrict__ flags,
                                                  f16_t* __restrict__ ctx,
                                                  int seq_len) {
    __shared__ __align__(16) f16_t Ksh[2][4096];      // 2 sub-tiles, swizzled col-group ^ (row&7)
    __shared__ __align__(16) f16_t Vsh[2][4096];      // 2 sub-tiles of V^T [d][key]
    __shared__ __align__(16) f16_t Psh[4][16 * 132];  // stride 132: conflict-free stores

    const int tid  = threadIdx.x;
    const int wv   = tid >> 6;
    const int lane = tid & 63;
    const int quad = lane >> 4;
    const int l15  = lane & 15;
    const int bh   = blockIdx.y;
    const int b    = bh >> 4;
    const int h    = bh & 15;
    const int q0   = blockIdx.x * 64 + wv * 16;

    const long kb = (long)bh * SS * DKK;

    f16x8 qf[2];
    {
        const f16_t* pq = Qp + kb + (long)(q0 + l15) * DKK + quad * 8;
        qf[0] = *(const f16x8*)pq;
        qf[1] = *(const f16x8*)(pq + 32);
        const f16_t qs = (f16_t)(8.0f * 1.44269504088896f);
#pragma unroll
        for (int j = 0; j < 8; ++j) { qf[0][j] *= qs; qf[1][j] *= qs; }
    }

    f16x8 ones;
#pragma unroll
    for (int j = 0; j < 8; ++j) ones[j] = (f16_t)1.0f;

    f32x4 o[4], lacc;
    float m[4];
#pragma unroll
    for (int r = 0; r < 4; ++r) {
        o[r] = (f32x4){0.f, 0.f, 0.f, 0.f};
        m[r] = -1e30f;
    }
    lacc = (f32x4){0.f, 0.f, 0.f, 0.f};

    const int* mrow = mask + b * SS;
    const int* frow = flags + b * (SS / 128);

    const int srow8 = lane >> 3;
    const int gcolB = ((lane & 7) ^ srow8) * 8;

#pragma unroll 1
    for (int kt = 0; kt < seq_len; kt += 128) {
#pragma unroll
        for (int c = 0; c < 2; ++c) {
            const int kc = kt + c * 64;
#pragma unroll
            for (int p = 0; p < 2; ++p) {
                const int i = wv * 2 + p;
                const int row = i * 8 + srow8;
                GLD_LDS(Kp + kb + (long)(kc + row) * DKK + gcolB, &Ksh[c][i * 512]);
                GLD_LDS(Vtp + kb + (long)row * SS + kc + gcolB, &Vsh[c][i * 512]);
            }
        }
        __syncthreads();

        f32x4 s[8];
#pragma unroll
        for (int nt = 0; nt < 8; ++nt) s[nt] = (f32x4){0.f, 0.f, 0.f, 0.f};
#pragma unroll
        for (int nt = 0; nt < 8; ++nt) {
            const int c = nt >> 2;
            const int kr = (nt & 3) * 16 + l15;
#pragma unroll
            for (int dt = 0; dt < 2; ++dt) {
                f16x8 kf = *(const f16x8*)&Ksh[c][kr * 64 + (((dt * 4 + quad) ^ (l15 & 7)) << 3)];
                s[nt] = __builtin_amdgcn_mfma_f32_16x16x32_f16(qf[dt], kf, s[nt], 0, 0, 0);
            }
        }

        if (!frow[kt >> 7]) {
#pragma unroll
            for (int nt = 0; nt < 8; ++nt) {
                int keep = mrow[kt + nt * 16 + l15];
#pragma unroll
                for (int r = 0; r < 4; ++r)
                    s[nt][r] = keep ? s[nt][r] : -1e30f;
            }
        }

        float tm[4];
#pragma unroll
        for (int r = 0; r < 4; ++r) {
            tm[r] = fmaxf(fmaxf(fmaxf(s[0][r], s[1][r]), fmaxf(s[2][r], s[3][r])),
                          fmaxf(fmaxf(s[4][r], s[5][r]), fmaxf(s[6][r], s[7][r])));
        }
#pragma unroll
        for (int off = 1; off < 16; off <<= 1) {
#pragma unroll
            for (int r = 0; r < 4; ++r) tm[r] = fmaxf(tm[r], __shfl_xor(tm[r], off));
        }

        float alpha[4];
#pragma unroll
        for (int r = 0; r < 4; ++r) {
            float mn = fmaxf(m[r], tm[r]);
            alpha[r] = exp2f(m[r] - mn);
            m[r] = mn;
        }

#pragma unroll
        for (int nt = 0; nt < 8; ++nt) {
#pragma unroll
            for (int r = 0; r < 4; ++r) {
                float p = exp2f(s[nt][r] - m[r]);
                Psh[wv][(quad * 4 + r) * 132 + nt * 16 + l15] = (f16_t)p;
            }
        }

#pragma unroll
        for (int t = 0; t < 4; ++t)
#pragma unroll
            for (int r = 0; r < 4; ++r) o[t][r] *= alpha[r];
#pragma unroll
        for (int r = 0; r < 4; ++r) lacc[r] *= alpha[r];

#pragma unroll
        for (int kk = 0; kk < 4; ++kk) {
            const int c = kk >> 1;
            const int kk2 = kk & 1;
            f16x4 pa = *(const f16x4*)&Psh[wv][l15 * 132 + kk * 32 + quad * 8];
            f16x4 pb = *(const f16x4*)&Psh[wv][l15 * 132 + kk * 32 + quad * 8 + 4];
            f16x8 pf = __builtin_shufflevector(pa, pb, 0, 1, 2, 3, 4, 5, 6, 7);
#pragma unroll
            for (int t = 0; t < 4; ++t) {
                const int vr = t * 16 + l15;
                f16x8 vf = *(const f16x8*)&Vsh[c][vr * 64 + (((kk2 * 4 + quad) ^ (l15 & 7)) << 3)];
                o[t] = __builtin_amdgcn_mfma_f32_16x16x32_f16(pf, vf, o[t], 0, 0, 0);
            }
            lacc = __builtin_amdgcn_mfma_f32_16x16x32_f16(pf, ones, lacc, 0, 0, 0);
        }
        __syncthreads();
    }

    float inv[4];
#pragma unroll
    for (int r = 0; r < 4; ++r) inv[r] = 1.0f / lacc[r];
#pragma unroll
    for (int t = 0; t < 4; ++t) {
        int d = t * 16 + l15;
#pragma unroll
        for (int r = 0; r < 4; ++r) {
            int tok = b * SS + q0 + quad * 4 + r;
            ctx[(long)tok * DD + h * DKK + d] = (f16_t)(o[t][r] * inv[r]);
        }
    }
}

// ---------------------------------------------------------------- launch
extern "C" void kernel_launch(void* const* d_in, const int* in_sizes, int n_in,
                              void* d_out, int out_size, void* d_ws, size_t ws_size,
                              hipStream_t stream) {
    const float* x  = (const float*)d_in[0];
    const int* mask = (const int*)d_in[1];
    const float* Wq = (const float*)d_in[2];
    const float* bq = (const float*)d_in[3];
    const float* Wk = (const float*)d_in[4];
    const float* bk = (const float*)d_in[5];
    const float* Wv = (const float*)d_in[6];
    const float* bv = (const float*)d_in[7];
    const float* Wo = (const float*)d_in[8];
    const float* bo = (const float*)d_in[9];
    float* out = (float*)d_out;

    const long NX = (long)BB * SS * DD;  // 4194304
    const long NW = (long)DD * DD;       // 1048576

    char* ws = (char*)d_ws;
    f16_t* xf   = (f16_t*)ws; ws += NX * 2;
    f16_t* wqkh = (f16_t*)ws; ws += 2 * NW * 2;
    f16_t* wqkl = (f16_t*)ws; ws += 2 * NW * 2;
    f16_t* wvf  = (f16_t*)ws; ws += NW * 2;
    f16_t* wof  = (f16_t*)ws; ws += NW * 2;
    f16_t* qf   = (f16_t*)ws; ws += NX * 2;
    f16_t* kf   = (f16_t*)ws; ws += NX * 2;
    f16_t* vt   = (f16_t*)ws; ws += NX * 2;
    f16_t* ctx  = (f16_t*)ws; ws += NX * 2;
    int*   flg  = (int*)ws;   ws += 64 * 4;

    cast_x_flags<<<2048, 256, 0, stream>>>(x, xf, mask, flg, (int)NX);
    cast_wqk<<<2048, 256, 0, stream>>>(Wq, Wk, wqkh, wqkl, (int)NW);
    cast_wvo<<<2048, 256, 0, stream>>>(Wv, Wo, wvf, wof, (int)NW);

    dim3 gqkv(3 * DD / 128, (BB * SS) / 128);  // (24, 32) = 768 blocks
    gemm_qkv<<<gqkv, 256, 0, stream>>>(xf, wqkh, wqkl, wvf, bq, bk, bv, qf, kf, vt, DD);

    dim3 agrid(SS / 64, BH);  // (32, 32) = 1024 blocks
    attn_mfma5<<<agrid, 256, 0, stream>>>(qf, kf, vt, mask, flg, ctx, SS);

    dim3 go(DD / 128, (BB * SS) / 64);  // (8, 64) = 512 blocks
    gemm_o<<<go, 256, 0, stream>>>(ctx, wof, bo, out, DD, DD);
}